// Round 1
// baseline (243.647 us; speedup 1.0000x reference)
//
#include <hip/hip_runtime.h>

typedef unsigned short u16;
typedef unsigned int u32;
typedef __attribute__((ext_vector_type(8))) __bf16 bf16x8;
typedef __attribute__((ext_vector_type(4))) float f32x4;

#define LOG2E 1.44269504088896340736f

__device__ __forceinline__ u16 f2bf(float f) {
  u32 u = __builtin_bit_cast(u32, f);
  u += 0x7fffu + ((u >> 16) & 1u);
  return (u16)(u >> 16);
}

__device__ __forceinline__ void async_copy16(const u16* g, u16* l) {
  __builtin_amdgcn_global_load_lds((const __attribute__((address_space(1))) void*)g,
                                   (__attribute__((address_space(3))) void*)l,
                                   16, 0, 0);
}

__device__ __forceinline__ bf16x8 ldb8(const u16* p) {
  return *(const bf16x8*)p;
}

// ---------------------------------------------------------------------------
// Kernel 1: fused f32 -> bf16 conversion of [query, key, value, Wq, Wk, Wv, Wo]
// into one contiguous bf16 region (16M elements).
// ---------------------------------------------------------------------------
__global__ __launch_bounds__(256) void convert_kernel(
    const float* __restrict__ q, const float* __restrict__ k, const float* __restrict__ v,
    const float* __restrict__ wq, const float* __restrict__ wk,
    const float* __restrict__ wv, const float* __restrict__ wo,
    u16* __restrict__ out)
{
  size_t t = (size_t)blockIdx.x * 256 + threadIdx.x;  // 0 .. 2M-1
  size_t e = t * 8;
  const float* src;
  size_t off;
  if (e < 12582912) {            // 3 x 4M qkv region
    int which = (int)(e >> 22);
    src = (which == 0) ? q : ((which == 1) ? k : v);
    off = e & 4194303;
  } else {                        // 4 x 1M weight region
    size_t r = e - 12582912;
    int which = (int)(r >> 20);
    src = (which == 0) ? wq : ((which == 1) ? wk : ((which == 2) ? wv : wo));
    off = r & 1048575;
  }
  float4 f0 = *(const float4*)(src + off);
  float4 f1 = *(const float4*)(src + off + 4);
  ushort4 u0, u1;
  u0.x = f2bf(f0.x); u0.y = f2bf(f0.y); u0.z = f2bf(f0.z); u0.w = f2bf(f0.w);
  u1.x = f2bf(f1.x); u1.y = f2bf(f1.y); u1.z = f2bf(f1.z); u1.w = f2bf(f1.w);
  *(ushort4*)(out + e) = u0;
  *(ushort4*)(out + e + 4) = u1;
}

// ---------------------------------------------------------------------------
// bf16 GEMM core: C[M=4096, N=1024] = A[M,1024] @ W[N,1024]^T + bias
// 128x128 tile, BK=32, 4 waves (2x2), 16x16x32 MFMA, global_load_lds staging.
// MODE 0: bf16 out, permuted [b,h,s,64], value scaled by `scale`
// MODE 1: bf16 out, transposed [b,h,64,s]  (for V)
// MODE 2: f32 out, plain row-major [M,N]
// ---------------------------------------------------------------------------
template <int MODE>
__device__ __forceinline__ void gemm128(
    const u16* __restrict__ A, const u16* __restrict__ W,
    const float* __restrict__ bias, void* __restrict__ out,
    float scale, u16* As, u16* Bs)
{
  const int tid = threadIdx.x;
  const int wid = tid >> 6, lane = tid & 63;
  const int g = lane >> 4, l16 = lane & 15;
  const int wr = wid >> 1, wc = wid & 1;
  const int brow = blockIdx.x * 128, bcol = blockIdx.y * 128;

  f32x4 acc[4][4] = {};
  const u16* Ab = A + (size_t)brow * 1024;
  const u16* Wb = W + (size_t)bcol * 1024;

  for (int kt = 0; kt < 32; ++kt) {
    const int k0 = kt * 32;
    // stage A and B tiles: 512 x 16B chunks each, 2 per thread per matrix
#pragma unroll
    for (int i = 0; i < 2; ++i) {
      const int chunk = i * 256 + wid * 64 + lane;
      const size_t goff = (size_t)(chunk >> 2) * 1024 + k0 + (chunk & 3) * 8;
      const int lbase = (i * 256 + wid * 64) * 8;  // elements; HW adds lane*16B
      async_copy16(Ab + goff, As + lbase);
      async_copy16(Wb + goff, Bs + lbase);
    }
    __syncthreads();  // drains vmcnt before barrier

    bf16x8 a[4], b[4];
#pragma unroll
    for (int m = 0; m < 4; ++m)
      a[m] = ldb8(As + ((wr * 64 + m * 16 + l16) * 32 + g * 8));
#pragma unroll
    for (int n = 0; n < 4; ++n)
      b[n] = ldb8(Bs + ((wc * 64 + n * 16 + l16) * 32 + g * 8));
#pragma unroll
    for (int m = 0; m < 4; ++m)
#pragma unroll
      for (int n = 0; n < 4; ++n)
        acc[m][n] = __builtin_amdgcn_mfma_f32_16x16x32_bf16(a[m], b[n], acc[m][n], 0, 0, 0);
    __syncthreads();
  }

  // epilogue
#pragma unroll
  for (int m = 0; m < 4; ++m) {
    const int mg = brow + wr * 64 + m * 16 + g * 4;  // + j
#pragma unroll
    for (int n = 0; n < 4; ++n) {
      const int cg = bcol + wc * 64 + n * 16 + l16;
      const float bb = bias[cg];
      if constexpr (MODE == 0) {
        const int h = cg >> 6, d = cg & 63;
#pragma unroll
        for (int j = 0; j < 4; ++j) {
          const int row = mg + j;
          const int bb_ = row >> 11, s = row & 2047;
          ((u16*)out)[(((size_t)(bb_ * 16 + h) * 2048 + s) << 6) + d] =
              f2bf((acc[m][n][j] + bb) * scale);
        }
      } else if constexpr (MODE == 1) {
        const int h = cg >> 6, d = cg & 63;
        const int bb_ = mg >> 11, s0 = mg & 2047;
        ushort4 pk;
        pk.x = f2bf(acc[m][n][0] + bb);
        pk.y = f2bf(acc[m][n][1] + bb);
        pk.z = f2bf(acc[m][n][2] + bb);
        pk.w = f2bf(acc[m][n][3] + bb);
        *(ushort4*)((u16*)out + ((size_t)(bb_ * 16 + h) * 64 + d) * 2048 + s0) = pk;
      } else {
#pragma unroll
        for (int j = 0; j < 4; ++j) {
          const int row = mg + j;
          ((float*)out)[(size_t)row * 1024 + cg] = acc[m][n][j] + bb;
        }
      }
    }
  }
}

__global__ __launch_bounds__(256) void qkv_gemm_kernel(
    const u16* __restrict__ xq, const u16* __restrict__ xk, const u16* __restrict__ xv,
    const u16* __restrict__ wq, const u16* __restrict__ wk, const u16* __restrict__ wv,
    const float* __restrict__ bq, const float* __restrict__ bk, const float* __restrict__ bv,
    u16* __restrict__ oq, u16* __restrict__ ok, u16* __restrict__ ov)
{
  __shared__ u16 As[4096];
  __shared__ u16 Bs[4096];
  const int z = blockIdx.z;
  if (z == 0)      gemm128<0>(xq, wq, bq, oq, 0.125f, As, Bs);  // Q, pre-scaled 1/sqrt(64)
  else if (z == 1) gemm128<0>(xk, wk, bk, ok, 1.0f, As, Bs);    // K
  else             gemm128<1>(xv, wv, bv, ov, 1.0f, As, Bs);    // V transposed
}

__global__ __launch_bounds__(256) void out_gemm_kernel(
    const u16* __restrict__ a, const u16* __restrict__ w,
    const float* __restrict__ bias, float* __restrict__ o)
{
  __shared__ u16 As[4096];
  __shared__ u16 Bs[4096];
  gemm128<2>(a, w, bias, o, 1.0f, As, Bs);
}

// ---------------------------------------------------------------------------
// Kernel 3: flash attention. Grid (S/128, B*H), 256 threads = 4 waves.
// Each wave owns 32 q-rows, iterates 64-key tiles with online softmax.
// Q/K: [b,h,s,64] bf16, V: [b,h,64,s] bf16 (transposed), out: [b,s,h*64+d] bf16
// ---------------------------------------------------------------------------
__global__ __launch_bounds__(256) void attn_kernel(
    const u16* __restrict__ qp, const u16* __restrict__ kp,
    const u16* __restrict__ vt, u16* __restrict__ ao)
{
  __shared__ u16 Plds[4 * 32 * 64];  // per-wave 32x64 bf16 P tile
  const int wid = threadIdx.x >> 6, lane = threadIdx.x & 63;
  const int g = lane >> 4, l16 = lane & 15;
  const int bh = blockIdx.y;                 // b*16 + h
  const int q0 = blockIdx.x * 128 + wid * 32;

  const u16* Q = qp + ((size_t)bh * 2048 + q0) * 64;
  const u16* K = kp + (size_t)bh * 2048 * 64;
  const u16* V = vt + (size_t)bh * 64 * 2048;
  u16* P = Plds + wid * 32 * 64;

  bf16x8 aq[2][2];
#pragma unroll
  for (int r = 0; r < 2; ++r)
#pragma unroll
    for (int c = 0; c < 2; ++c)
      aq[r][c] = ldb8(Q + (r * 16 + l16) * 64 + c * 32 + g * 8);

  f32x4 outa[2][4] = {};
  float mrun[2][4], lrun[2][4];
#pragma unroll
  for (int r = 0; r < 2; ++r)
#pragma unroll
    for (int j = 0; j < 4; ++j) { mrun[r][j] = -1e30f; lrun[r][j] = 0.f; }

  const f32x4 zf = {0.f, 0.f, 0.f, 0.f};

  for (int kt = 0; kt < 32; ++kt) {
    const int kb = kt * 64;
    f32x4 s[2][4];
#pragma unroll
    for (int kk = 0; kk < 4; ++kk) {
      const bf16x8 bk0 = ldb8(K + (size_t)(kb + kk * 16 + l16) * 64 + g * 8);
      const bf16x8 bk1 = ldb8(K + (size_t)(kb + kk * 16 + l16) * 64 + 32 + g * 8);
#pragma unroll
      for (int r = 0; r < 2; ++r) {
        f32x4 t = __builtin_amdgcn_mfma_f32_16x16x32_bf16(aq[r][0], bk0, zf, 0, 0, 0);
        s[r][kk] = __builtin_amdgcn_mfma_f32_16x16x32_bf16(aq[r][1], bk1, t, 0, 0, 0);
      }
    }
    // online softmax; rows live in the 16-lane group (row = g*4+j), cols = kk*16+l16
#pragma unroll
    for (int r = 0; r < 2; ++r) {
#pragma unroll
      for (int j = 0; j < 4; ++j) {
        float mx = fmaxf(fmaxf(s[r][0][j], s[r][1][j]), fmaxf(s[r][2][j], s[r][3][j]));
        mx = fmaxf(mx, __shfl_xor(mx, 1));
        mx = fmaxf(mx, __shfl_xor(mx, 2));
        mx = fmaxf(mx, __shfl_xor(mx, 4));
        mx = fmaxf(mx, __shfl_xor(mx, 8));
        const float mnew = fmaxf(mrun[r][j], mx);
        const float corr = exp2f((mrun[r][j] - mnew) * LOG2E);
        mrun[r][j] = mnew;
        const int row = r * 16 + g * 4 + j;
        float ps = 0.f;
#pragma unroll
        for (int kk = 0; kk < 4; ++kk) {
          const float p = exp2f((s[r][kk][j] - mnew) * LOG2E);
          ps += p;
          const int col = kk * 16 + l16;
          const int sch = (col >> 3) ^ (row & 7);   // XOR chunk swizzle vs bank conflicts
          P[row * 64 + sch * 8 + (col & 7)] = f2bf(p);
        }
        ps += __shfl_xor(ps, 1);
        ps += __shfl_xor(ps, 2);
        ps += __shfl_xor(ps, 4);
        ps += __shfl_xor(ps, 8);
        lrun[r][j] = lrun[r][j] * corr + ps;
#pragma unroll
        for (int df = 0; df < 4; ++df) outa[r][df][j] *= corr;
      }
    }
    // read P back as A-fragments (same-wave LDS, in-order)
    bf16x8 pa[2][2];
#pragma unroll
    for (int r = 0; r < 2; ++r) {
      const int row = r * 16 + l16;
#pragma unroll
      for (int kc = 0; kc < 2; ++kc) {
        const int sch = (kc * 4 + g) ^ (row & 7);
        pa[r][kc] = ldb8(P + row * 64 + sch * 8);
      }
    }
    // PV: out[q, d] += P @ V, V^T layout [d][s]
#pragma unroll
    for (int df = 0; df < 4; ++df) {
      const bf16x8 bv0 = ldb8(V + (size_t)(df * 16 + l16) * 2048 + kb + g * 8);
      const bf16x8 bv1 = ldb8(V + (size_t)(df * 16 + l16) * 2048 + kb + 32 + g * 8);
#pragma unroll
      for (int r = 0; r < 2; ++r) {
        outa[r][df] = __builtin_amdgcn_mfma_f32_16x16x32_bf16(pa[r][0], bv0, outa[r][df], 0, 0, 0);
        outa[r][df] = __builtin_amdgcn_mfma_f32_16x16x32_bf16(pa[r][1], bv1, outa[r][df], 0, 0, 0);
      }
    }
  }

  // normalize + store bf16 to [b, s, h*64+d]
  const int b = bh >> 4, h = bh & 15;
#pragma unroll
  for (int r = 0; r < 2; ++r) {
#pragma unroll
    for (int j = 0; j < 4; ++j) {
      const float inv = 1.0f / lrun[r][j];
      const int srow = q0 + r * 16 + g * 4 + j;
#pragma unroll
      for (int df = 0; df < 4; ++df) {
        ao[((size_t)b * 2048 + srow) * 1024 + h * 64 + df * 16 + l16] =
            f2bf(outa[r][df][j] * inv);
      }
    }
  }
}

// ---------------------------------------------------------------------------
extern "C" void kernel_launch(void* const* d_in, const int* in_sizes, int n_in,
                              void* d_out, int out_size, void* d_ws, size_t ws_size,
                              hipStream_t stream) {
  const float* q  = (const float*)d_in[0];
  const float* k  = (const float*)d_in[1];
  const float* v  = (const float*)d_in[2];
  const float* Wq = (const float*)d_in[3];
  const float* bq = (const float*)d_in[4];
  const float* Wk = (const float*)d_in[5];
  const float* bk = (const float*)d_in[6];
  const float* Wv = (const float*)d_in[7];
  const float* bv = (const float*)d_in[8];
  const float* Wo = (const float*)d_in[9];
  const float* bo = (const float*)d_in[10];

  u16* ws = (u16*)d_ws;
  u16* xq   = ws;                  // query bf16   (4M)
  u16* xk   = ws + 4194304;        // key bf16     (4M)
  u16* xv   = ws + 8388608;        // value bf16   (4M)
  u16* wqb  = ws + 12582912;       // Wq bf16      (1M)
  u16* wkb  = ws + 13631488;
  u16* wvb  = ws + 14680064;
  u16* wob  = ws + 15728640;
  u16* qperm = ws + 16777216;      // Q  [b,h,s,64]  (4M)
  u16* kperm = ws + 20971520;      // K  [b,h,s,64]  (4M)
  u16* vtp   = ws + 25165824;      // V^T[b,h,64,s]  (4M)
  u16* aout  = ws + 29360128;      // attn out [b,s,1024] (4M)
  // total: 64 MB of workspace

  convert_kernel<<<8192, 256, 0, stream>>>(q, k, v, Wq, Wk, Wv, Wo, ws);
  qkv_gemm_kernel<<<dim3(32, 8, 3), 256, 0, stream>>>(xq, xk, xv, wqb, wkb, wvb,
                                                      bq, bk, bv, qperm, kperm, vtp);
  attn_kernel<<<dim3(16, 32), 256, 0, stream>>>(qperm, kperm, vtp, aout);
  out_gemm_kernel<<<dim3(32, 8), 256, 0, stream>>>(aout, wob, bo, (float*)d_out);
}